// Round 13
// baseline (123.206 us; speedup 1.0000x reference)
//
#include <hip/hip_runtime.h>
#include <cstdint>
#include <cstddef>

// Problem constants
#define B_   8
#define N_   4096
#define C_   256
#define C3_  768
#define NH_  8
#define CH_  32

// Workspace layout (in floats).
static const size_t OFF_QKV    = 0;          // [B*N, 768] fp32 (q|k|v). k cols reused as bf16 hi/lo of attn output
static const size_t OFF_CONVV  = 25165824;   // Xhl u16[32768][512] for gemm1, then kvpart
static const size_t OFF_KV     = 33554432;   // [B*h, 32, 32]
static const size_t OFF_WHL    = 33619968;   // Whl u16[1024][512]: rows 0..767 Wqkv, 768..1023 Wproj
static const size_t OFF_SPART  = 34144256;   // [B*h, 16, 32] column exp-sums

typedef __attribute__((ext_vector_type(4))) float f32x4;
typedef __attribute__((ext_vector_type(8))) short b16x8;   // 8 bf16 = 4 VGPRs

__device__ __forceinline__ unsigned short f2bf(float f) {
    unsigned u = __float_as_uint(f);
    return (unsigned short)((u + 0x7FFFu + ((u >> 16) & 1u)) >> 16);  // RTNE
}
__device__ __forceinline__ float bf2f(unsigned short h) {
    return __uint_as_float(((unsigned)h) << 16);
}

// ---------------------------------------------------------------------------
// Single launch converting x, Wqkv, Wproj to bf16 hi/lo pairs.
// x-branch XCD batch-affine.
// ---------------------------------------------------------------------------
__global__ __launch_bounds__(256) void convert_all(
    const float* __restrict__ x, const float* __restrict__ wqkv,
    const float* __restrict__ wproj, unsigned short* __restrict__ xhl,
    unsigned short* __restrict__ whl)
{
    int bid = blockIdx.x;
    const float* in;
    unsigned short* out;
    if (bid < 8192)      { in = x;     out = xhl;
                           bid = (bid & 7) * 1024 + (bid >> 3); }     // XCD b -> batch b
    else if (bid < 8384) { in = wqkv;  out = whl;                      bid -= 8192; }
    else                 { in = wproj; out = whl + (size_t)768 * 512;  bid -= 8384; }

    const int idx = bid * 256 + threadIdx.x;
    const int r = idx >> 6, q = idx & 63;
    const float4 v = *(const float4*)(in + (size_t)r * 256 + q * 4);
    const float f[4] = {v.x, v.y, v.z, v.w};
    unsigned short h[4], l[4];
#pragma unroll
    for (int t = 0; t < 4; ++t) {
        h[t] = f2bf(f[t]);
        l[t] = f2bf(f[t] - bf2f(h[t]));
    }
    unsigned short* o = out + (size_t)r * 512 + q * 4;
    ushort4 hv; hv.x = h[0]; hv.y = h[1]; hv.z = h[2]; hv.w = h[3];
    ushort4 lv; lv.x = l[0]; lv.y = l[1]; lv.z = l[2]; lv.w = l[3];
    *(ushort4*)(o)       = hv;
    *(ushort4*)(o + 256) = lv;
}

// ---------------------------------------------------------------------------
// MFMA GEMM, bf16x3 fp32 emulation, K = 256 (8 K-steps of 32).
// NEW STRUCTURE (never-drain 3-deep pipeline):
//   BM=256 x BN=128 tile, 8 waves (4M x 2N), per-wave 64x64 (4x4 frags) —
//   per-wave fragment/swizzle/MFMA/epilogue code identical to the verified
//   128x128 kernel. THREE LDS buffers (48 KB each): phase t computes tile t
//   from buf t%3 while staging tile t+2 (6 GLL/thread) into buf (t+2)%3;
//   end-of-phase s_waitcnt vmcnt(6) retires tile t+1 (staged one full phase
//   earlier) while tile t+2's loads stay in flight across the barrier.
//   One barrier per K-step; vmcnt never drains to 0 until the tail.
// ---------------------------------------------------------------------------
__global__ __launch_bounds__(512, 2) void gemm_hl_mfma(
    const unsigned short* __restrict__ Ah, int lda,
    const unsigned short* __restrict__ Bh, int ldb,
    float* __restrict__ Cc, int ldc,
    const float* __restrict__ bias)
{
    // buffer layout (u16): A-hi [256][32] @0, A-lo @16384B, B-hi [128][32]
    // @32768B, B-lo @40960B; buffer stride 49152 B; 3 buffers = 144 KB.
    __shared__ __align__(128) unsigned short sm[3 * 24576];
    const int tid  = threadIdx.x;          // 0..511
    const int lane = tid & 63;
    const int wv   = tid >> 6;             // 0..7
    const int wm   = wv >> 1, wn = wv & 1; // 4M x 2N wave grid

    // XCD-chunked swizzle (nwg % 8 == 0 for both launches)
    const int nbx = gridDim.x;
    const int nwg = nbx * gridDim.y;
    const int bid = blockIdx.y * nbx + blockIdx.x;
    const int cpx = nwg >> 3;
    const int sw  = (bid & 7) * cpx + (bid >> 3);
    const int by  = sw / nbx;
    const int bx  = sw - by * nbx;
    const size_t m0 = (size_t)by * 256;
    const int n0 = bx * 128;

    const unsigned short* Al = Ah + 256;
    const unsigned short* Bl = Bh + 256;

    f32x4 acc[4][4];
#pragma unroll
    for (int i = 0; i < 4; ++i)
#pragma unroll
        for (int j = 0; j < 4; ++j) {
            f32x4 z = {0.f, 0.f, 0.f, 0.f};
            acc[i][j] = z;
        }

#define GLL(gp, ldsByteOff)                                                          \
    __builtin_amdgcn_global_load_lds(                                                \
        (const __attribute__((address_space(1))) void*)(gp),                         \
        (__attribute__((address_space(3))) void*)(((char*)sm) + (ldsByteOff)), 16, 0, 0)

    // Stage one K-tile (6 GLLs/thread): A-hi/lo cells {tid, tid+512} of 1024,
    // B-hi/lo cell tid of 512. LDS linear in cell; source k-slot pre-swizzled
    // with the read-side involution slot ^ ((row>>1)&3).
#define STAGE(bufIdx, k0)                                                            \
    {                                                                                \
        const unsigned bb_ = (unsigned)(bufIdx) * 49152u;                            \
        {                                                                            \
            const int c_ = tid;                                                      \
            const int row_ = c_ >> 2;                                                \
            const int sl_  = (c_ & 3) ^ ((row_ >> 1) & 3);                           \
            const size_t ga_ = (size_t)(m0 + row_) * lda + (k0) + sl_ * 8;           \
            GLL(Ah + ga_, bb_ + (unsigned)c_ * 16u);                                 \
            GLL(Al + ga_, bb_ + 16384u + (unsigned)c_ * 16u);                        \
        }                                                                            \
        {                                                                            \
            const int c_ = tid + 512;                                                \
            const int row_ = c_ >> 2;                                                \
            const int sl_  = (c_ & 3) ^ ((row_ >> 1) & 3);                           \
            const size_t ga_ = (size_t)(m0 + row_) * lda + (k0) + sl_ * 8;           \
            GLL(Ah + ga_, bb_ + (unsigned)c_ * 16u);                                 \
            GLL(Al + ga_, bb_ + 16384u + (unsigned)c_ * 16u);                        \
        }                                                                            \
        {                                                                            \
            const int c_ = tid;                                                      \
            const int row_ = c_ >> 2;                                                \
            const int sl_  = (c_ & 3) ^ ((row_ >> 1) & 3);                           \
            const size_t gb_ = (size_t)(n0 + row_) * ldb + (k0) + sl_ * 8;           \
            GLL(Bh + gb_, bb_ + 32768u + (unsigned)c_ * 16u);                        \
            GLL(Bl + gb_, bb_ + 40960u + (unsigned)c_ * 16u);                        \
        }                                                                            \
    }

    // ---- prologue: tiles 0 and 1 staged; retire tile 0 (6 of 12 left) ----
    STAGE(0, 0);
    STAGE(1, 32);
    asm volatile("s_waitcnt vmcnt(6)" ::: "memory");
    __builtin_amdgcn_s_barrier();
    __builtin_amdgcn_sched_barrier(0);

#pragma unroll
    for (int t = 0; t < 8; ++t) {
        const int buf = t % 3;                 // constant after unroll
        if (t + 2 < 8) STAGE((t + 2) % 3, (t + 2) * 32);

        const char* base = (const char*)sm + buf * 49152;
        const int sR = lane >> 4;
        b16x8 fah[4], fal[4], fbh[4], fbl[4];
#pragma unroll
        for (int i = 0; i < 4; ++i) {
            const int ra = wm * 64 + i * 16 + (lane & 15);
            const int oa = ra * 64 + ((sR ^ ((ra >> 1) & 3)) * 16);
            fah[i] = *(const b16x8*)(base + oa);
            fal[i] = *(const b16x8*)(base + 16384 + oa);
            const int rb = wn * 64 + i * 16 + (lane & 15);
            const int ob = rb * 64 + ((sR ^ ((rb >> 1) & 3)) * 16);
            fbh[i] = *(const b16x8*)(base + 32768 + ob);
            fbl[i] = *(const b16x8*)(base + 40960 + ob);
        }
        // Swapped operands: D-row <-> B row (n), D-col <-> A row (m).
        __builtin_amdgcn_s_setprio(1);
#pragma unroll
        for (int i = 0; i < 4; ++i)
#pragma unroll
            for (int j = 0; j < 4; ++j) {
                acc[i][j] = __builtin_amdgcn_mfma_f32_16x16x32_bf16(fbh[j], fah[i], acc[i][j], 0, 0, 0);
                acc[i][j] = __builtin_amdgcn_mfma_f32_16x16x32_bf16(fbl[j], fah[i], acc[i][j], 0, 0, 0);
                acc[i][j] = __builtin_amdgcn_mfma_f32_16x16x32_bf16(fbh[j], fal[i], acc[i][j], 0, 0, 0);
            }
        __builtin_amdgcn_s_setprio(0);
        __builtin_amdgcn_sched_barrier(0);

        // end-of-phase: tile t+1 must be resident for the next phase; tile
        // t+2's 6 loads (issued this phase) stay in flight.
        if (t < 6) {
            asm volatile("s_waitcnt vmcnt(6)" ::: "memory");
        } else if (t == 6) {
            asm volatile("s_waitcnt vmcnt(0)" ::: "memory");
        }
        if (t < 7) {
            __builtin_amdgcn_s_barrier();
            __builtin_amdgcn_sched_barrier(0);
        }
    }
#undef STAGE
#undef GLL

    // ---- epilogue: lane holds C[m][n..n+3] -> float4 stores ----
#pragma unroll
    for (int j = 0; j < 4; ++j) {
        const int nb = n0 + wn * 64 + j * 16 + ((lane >> 4) << 2);
        float4 bv = {0.f, 0.f, 0.f, 0.f};
        if (bias) bv = *(const float4*)(bias + nb);
#pragma unroll
        for (int i = 0; i < 4; ++i) {
            const size_t m = m0 + wm * 64 + i * 16 + (lane & 15);
            float4 o;
            o.x = acc[i][j][0] + bv.x;
            o.y = acc[i][j][1] + bv.y;
            o.z = acc[i][j][2] + bv.z;
            o.w = acc[i][j][3] + bv.w;
            *(float4*)(Cc + m * ldc + nb) = o;
        }
    }
}

// ---------------------------------------------------------------------------
// kvpart + column exp-sums. XCD batch-affine. Unchanged from R12.
// ---------------------------------------------------------------------------
__global__ __launch_bounds__(256) void kv_partial(
    const float* __restrict__ qkv, float* __restrict__ kvpart,
    float* __restrict__ sp)
{
    const int bid0  = blockIdx.x;   // 1024 blocks
    const int bid   = (bid0 & 7) * 128 + (bid0 >> 3);   // XCD b -> batch b
    const int chunk = bid & 15;
    const int bh    = bid >> 4;
    const int b     = bh >> 3, hh = bh & 7;
    const int tid   = threadIdx.x;

    __shared__ float smem[4096];
    float* ks = smem;
    float* vs = smem + 2048;

    const int c  = tid & 31;
    const int rs = tid >> 5;
    const float* kbase = qkv + (size_t)b * N_ * C3_ + C_ + hh * 32 + c;
    const float* vbase = qkv + (size_t)b * N_ * C3_ + 2 * C_ + hh * 32 + c;

    const int s   = tid >> 6;
    const int lan = tid & 63;
    const int ckg = (lan >> 3) & 7;
    const int cvg = lan & 7;

    float acc[4][4] = {};
    float sStage = 0.f;

    for (int t = 0; t < 4; ++t) {
        const int nb = chunk * 256 + t * 64;
#pragma unroll
        for (int u = 0; u < 8; ++u) {
            const int i = u * 8 + rs;
            const size_t off = (size_t)(nb + i) * C3_;
            const float ev = __expf(kbase[off]);
            ks[i * 32 + c] = ev;
            sStage += ev;
            vs[i * 32 + c] = vbase[off];
        }
        __syncthreads();
#pragma unroll
        for (int i = 0; i < 16; ++i) {
            const int row = s * 16 + i;
            const float4 k4 = *(const float4*)&ks[row * 32 + ckg * 4];
            const float4 v4 = *(const float4*)&vs[row * 32 + cvg * 4];
            const float ka[4] = {k4.x, k4.y, k4.z, k4.w};
            const float va[4] = {v4.x, v4.y, v4.z, v4.w};
#pragma unroll
            for (int a = 0; a < 4; ++a)
#pragma unroll
                for (int bb = 0; bb < 4; ++bb)
                    acc[a][bb] = fmaf(ka[a], va[bb], acc[a][bb]);
        }
        __syncthreads();
    }

#pragma unroll
    for (int a = 0; a < 4; ++a) {
        float4 w;
        w.x = acc[a][0]; w.y = acc[a][1]; w.z = acc[a][2]; w.w = acc[a][3];
        *(float4*)&smem[s * 1024 + (ckg * 4 + a) * 32 + cvg * 4] = w;
    }
    __syncthreads();
    {
        const int i0 = tid * 4;
        float4 r0 = *(const float4*)&smem[i0];
        float4 r1 = *(const float4*)&smem[1024 + i0];
        float4 r2 = *(const float4*)&smem[2048 + i0];
        float4 r3 = *(const float4*)&smem[3072 + i0];
        float4 o;
        o.x = r0.x + r1.x + r2.x + r3.x;
        o.y = r0.y + r1.y + r2.y + r3.y;
        o.z = r0.z + r1.z + r2.z + r3.z;
        o.w = r0.w + r1.w + r2.w + r3.w;
        *(float4*)&kvpart[(size_t)bid * 1024 + i0] = o;
    }
    __syncthreads();
    smem[rs * 32 + c] = sStage;
    __syncthreads();
    if (tid < 32) {
        float S = 0.f;
#pragma unroll
        for (int i = 0; i < 8; ++i) S += smem[i * 32 + tid];
        sp[(size_t)bid * 32 + tid] = S;
    }
}

__global__ __launch_bounds__(1024) void kv_reduce(
    const float* __restrict__ kvpart, const float* __restrict__ sp,
    float* __restrict__ kv)
{
    const int bid0 = blockIdx.x;    // 64 blocks
    const int bh   = (bid0 & 7) * 8 + (bid0 >> 3);
    const int j  = threadIdx.x;
    const int ck = j >> 5;
    float s = 0.f, ssum = 0.f;
#pragma unroll
    for (int t = 0; t < 16; ++t) s += kvpart[(size_t)(bh * 16 + t) * 1024 + j];
#pragma unroll
    for (int t = 0; t < 16; ++t) ssum += sp[(size_t)(bh * 16 + t) * 32 + ck];
    kv[(size_t)bh * 1024 + j] = s / ssum;
}

// ---------------------------------------------------------------------------
// FUSED conv + combine. XCD batch-affine. Unchanged from R12.
// ---------------------------------------------------------------------------
__global__ __launch_bounds__(256) void attn_fused(
    float* __restrict__ qkv, const float* __restrict__ kv,
    const float* __restrict__ kern, const float* __restrict__ kbias)
{
    const int bid0 = blockIdx.x;     // 2048 blocks
    const int bid  = (bid0 & 7) * 256 + (bid0 >> 3);
    const int rb = bid & 255, b = bid >> 8;
    const int y  = rb >> 2;
    const int x0 = (rb & 3) * 16;
    const size_t row0 = (size_t)b * N_ + rb * 16;
    const int tid = threadIdx.x;

    __shared__ float kvs[8192];
    __shared__ float qs[16 * 288];
    __shared__ float cvs[16 * 256];

    {
        const float* kvsrc = kv + (size_t)b * 8192;
#pragma unroll
        for (int u = 0; u < 8; ++u) {
            const int idx = u * 1024 + tid * 4;
            *(float4*)&kvs[idx] = *(const float4*)&kvsrc[idx];
        }
    }
    const int sdst = (tid >> 5) * 36 + (tid & 31);
#pragma unroll
    for (int r = 0; r < 16; ++r)
        qs[r * 288 + sdst] = qkv[(row0 + r) * C3_ + tid];

    {
        const int c = tid;
        float kw[9];
#pragma unroll
        for (int q = 0; q < 9; ++q) kw[q] = kern[c * 9 + q];
        const float bb = kbias[c];

        const float* vb = qkv + (size_t)b * N_ * C3_ + 2 * C_ + c;
        float win[3][18];
#pragma unroll
        for (int dy = 0; dy < 3; ++dy) {
            const int yy = y + dy - 1;
            const bool oky = (yy >= 0) && (yy < 64);
#pragma unroll
            for (int dx = 0; dx < 18; ++dx) {
                const int xx = x0 + dx - 1;
                const bool ok = oky && (xx >= 0) && (xx < 64);
                win[dy][dx] = ok ? vb[(size_t)(yy * 64 + xx) * C3_] : 0.f;
            }
        }
#pragma unroll
        for (int xo = 0; xo < 16; ++xo) {
            float o = bb;
#pragma unroll
            for (int dy = 0; dy < 3; ++dy) {
                o = fmaf(kw[dy * 3 + 0], win[dy][xo + 0], o);
                o = fmaf(kw[dy * 3 + 1], win[dy][xo + 1], o);
                o = fmaf(kw[dy * 3 + 2], win[dy][xo + 2], o);
            }
            cvs[xo * 256 + c] = o;
        }
    }
    __syncthreads();

    const int rg  = tid >> 6;
    const int cg  = tid & 63;
    const int hh  = cg >> 3;
    const int cv0 = (cg & 7) * 4;
    const float scale = 0.17677669529663687f;

    float acc[4][4] = {};
    for (int ck = 0; ck < 32; ++ck) {
        const float4 kv4 = *(const float4*)&kvs[hh * 1024 + ck * 32 + cv0];
        const float kva[4] = {kv4.x, kv4.y, kv4.z, kv4.w};
#pragma unroll
        for (int ri = 0; ri < 4; ++ri) {
            const float qv = qs[(rg * 4 + ri) * 288 + hh * 36 + ck];
#pragma unroll
            for (int bb = 0; bb < 4; ++bb)
                acc[ri][bb] = fmaf(qv, kva[bb], acc[ri][bb]);
        }
    }

#pragma unroll
    for (int ri = 0; ri < 4; ++ri) {
        const int r = rg * 4 + ri;
        const float4 q4 = *(const float4*)&qs[r * 288 + hh * 36 + cv0];
        const float4 cw = *(const float4*)&cvs[r * 256 + cg * 4];
        const float qa[4]  = {q4.x, q4.y, q4.z, q4.w};
        const float cwa[4] = {cw.x, cw.y, cw.z, cw.w};
        unsigned short h[4], l[4];
#pragma unroll
        for (int bb = 0; bb < 4; ++bb) {
            const float t = fmaf(qa[bb], cwa[bb], scale * acc[ri][bb]);
            h[bb] = f2bf(t);
            l[bb] = f2bf(t - bf2f(h[bb]));
        }
        unsigned short* kreg = (unsigned short*)(qkv + (row0 + r) * C3_ + C_);
        ushort4 hv; hv.x = h[0]; hv.y = h[1]; hv.z = h[2]; hv.w = h[3];
        ushort4 lv; lv.x = l[0]; lv.y = l[1]; lv.z = l[2]; lv.w = l[3];
        *(ushort4*)&kreg[cg * 4]       = hv;
        *(ushort4*)&kreg[256 + cg * 4] = lv;
    }
}

// ---------------------------------------------------------------------------
extern "C" void kernel_launch(void* const* d_in, const int* in_sizes, int n_in,
                              void* d_out, int out_size, void* d_ws, size_t ws_size,
                              hipStream_t stream)
{
    const float* x     = (const float*)d_in[0];
    const float* Wqkv  = (const float*)d_in[1];
    const float* Wproj = (const float*)d_in[2];
    const float* bproj = (const float*)d_in[3];
    const float* kern  = (const float*)d_in[4];
    const float* kbias = (const float*)d_in[5];

    float* ws     = (float*)d_ws;
    float* qkv    = ws + OFF_QKV;
    float* kv     = ws + OFF_KV;
    float* spart  = ws + OFF_SPART;
    float* kvpart = ws + OFF_CONVV;                            // reuses xhl region (dead after gemm1)
    float* out    = (float*)d_out;

    unsigned short* xhl = (unsigned short*)(ws + OFF_CONVV);   // live only for gemm1
    unsigned short* whl = (unsigned short*)(ws + OFF_WHL);     // Wqkv rows 0..767, Wproj rows 768..1023

    // 0) fp32 -> bf16 hi/lo splits for all MFMA GEMM inputs (one launch)
    convert_all<<<8448, 256, 0, stream>>>(x, Wqkv, Wproj, xhl, whl);
    // 1) qkv = x @ Wqkv^T via bf16x3 MFMA   [32768 x 768]; 256x128 tiles, 8 waves
    gemm_hl_mfma<<<dim3(6, 128), 512, 0, stream>>>(xhl, 512, whl, 512, qkv, C3_, nullptr);
    // 2) kv = softmax(k)^T @ v per (b,h): split-N partials + reduce
    kv_partial<<<1024, 256, 0, stream>>>(qkv, kvpart, spart);
    kv_reduce<<<64, 1024, 0, stream>>>(kvpart, spart, kv);
    // 3) FUSED conv + combine (XCD batch-affine): tmp -> bf16 hi/lo into k-cols
    attn_fused<<<2048, 256, 0, stream>>>(qkv, kv, kern, kbias);
    // 4) out = tmp @ Wproj^T + bproj via bf16x3 MFMA   [32768 x 256]
    gemm_hl_mfma<<<dim3(2, 128), 512, 0, stream>>>((unsigned short*)qkv + 512, 1536,
                                                   whl + (size_t)768 * 512, 512, out, C_, bproj);
}

// Round 15
// 105.212 us; speedup vs baseline: 1.1710x; 1.1710x over previous
//
#include <hip/hip_runtime.h>
#include <cstdint>
#include <cstddef>

// Problem constants
#define B_   8
#define N_   4096
#define C_   256
#define C3_  768
#define NH_  8
#define CH_  32

// Workspace layout (in floats).
static const size_t OFF_QKV    = 0;          // [B*N, 768] fp32 (q|k|v). k cols reused as fp16 attn output for gemm2
static const size_t OFF_CONVV  = 25165824;   // Xh fp16[32768][256] for gemm1, then kvpart
static const size_t OFF_KV     = 33554432;   // [B*h, 32, 32]
static const size_t OFF_WHL    = 33619968;   // Whl fp16[1024][512]: hi cols 0..255, lo 256..511; rows 0..767 Wqkv, 768..1023 Wproj
static const size_t OFF_SPART  = 34144256;   // [B*h, 16, 32] column exp-sums

typedef __attribute__((ext_vector_type(4))) float f32x4;
typedef __attribute__((ext_vector_type(8))) _Float16 f16x8;   // 8 fp16 = 4 VGPRs

__device__ __forceinline__ unsigned short f2h(float f) {
    return __builtin_bit_cast(unsigned short, (_Float16)f);   // RTNE
}
__device__ __forceinline__ float h2f(unsigned short u) {
    return (float)__builtin_bit_cast(_Float16, u);
}

// ---------------------------------------------------------------------------
// Single launch converting x -> fp16 (single) and Wqkv/Wproj -> fp16 hi/lo.
// fp16 hi+lo represents W to ~2^-22 relative; fp16 x costs 2^-11 relative.
// x-branch XCD batch-affine.
// ---------------------------------------------------------------------------
__global__ __launch_bounds__(256) void convert_all(
    const float* __restrict__ x, const float* __restrict__ wqkv,
    const float* __restrict__ wproj, unsigned short* __restrict__ xh,
    unsigned short* __restrict__ whl)
{
    int bid = blockIdx.x;
    if (bid < 8192) {
        bid = (bid & 7) * 1024 + (bid >> 3);                  // XCD b -> batch b
        const int idx = bid * 256 + threadIdx.x;
        const int r = idx >> 6, q = idx & 63;
        const float4 v = *(const float4*)(x + (size_t)r * 256 + q * 4);
        ushort4 hv;
        hv.x = f2h(v.x); hv.y = f2h(v.y); hv.z = f2h(v.z); hv.w = f2h(v.w);
        *(ushort4*)(xh + (size_t)r * 256 + q * 4) = hv;
        return;
    }
    const float* in;
    unsigned short* out;
    if (bid < 8384) { in = wqkv;  out = whl;                      bid -= 8192; }
    else            { in = wproj; out = whl + (size_t)768 * 512;  bid -= 8384; }

    const int idx = bid * 256 + threadIdx.x;
    const int r = idx >> 6, q = idx & 63;
    const float4 v = *(const float4*)(in + (size_t)r * 256 + q * 4);
    const float f[4] = {v.x, v.y, v.z, v.w};
    unsigned short h[4], l[4];
#pragma unroll
    for (int t = 0; t < 4; ++t) {
        h[t] = f2h(f[t]);
        l[t] = f2h(f[t] - h2f(h[t]));
    }
    unsigned short* o = out + (size_t)r * 512 + q * 4;
    ushort4 hv; hv.x = h[0]; hv.y = h[1]; hv.z = h[2]; hv.w = h[3];
    ushort4 lv; lv.x = l[0]; lv.y = l[1]; lv.z = l[2]; lv.w = l[3];
    *(ushort4*)(o)       = hv;
    *(ushort4*)(o + 256) = lv;
}

// ---------------------------------------------------------------------------
// MFMA GEMM, fp16 emulation of fp32: C = A_fp16 @ (Wh + Wl)^T (+ bias).
// A: fp16 single [m][lda]; B: fp16 hi at Bh[n][ldb], lo at +256.
// 128x128 tile, BK=32, 4 waves (2x2 of 64x64) — R12's verified counted-vmcnt
// double-buffer skeleton. Per buffer: A 8 KB | Bh 8 KB | Bl 8 KB = 24 KB;
// 2 buffers = 48 KB -> 3 blocks/CU. 6 GLL/thread/tile, vmcnt(6).
// FIX vs R14: every GLL's per-lane LDS dest is cell (p*256+tid)*16 — stride
// 16 contiguous in lane order, as global_load_lds requires (wave-uniform
// base + lane*16). R14's tid*2 B-pattern violated this -> half of B
// unwritten -> NaN.
// ---------------------------------------------------------------------------
__global__ __launch_bounds__(256, 3) void gemm_f16_mfma(
    const unsigned short* __restrict__ Ah, int lda,
    const unsigned short* __restrict__ Bh, int ldb,
    float* __restrict__ Cc, int ldc,
    const float* __restrict__ bias)
{
    __shared__ __align__(128) unsigned short sm[2][12288];   // 48 KB
    const int tid  = threadIdx.x;
    const int lane = tid & 63;
    const int wv   = tid >> 6;
    const int wm   = wv >> 1, wn = wv & 1;

    // XCD-chunked swizzle (nwg % 8 == 0 for both launches)
    const int nbx = gridDim.x;
    const int nwg = nbx * gridDim.y;
    const int bid = blockIdx.y * nbx + blockIdx.x;
    const int cpx = nwg >> 3;
    const int sw  = (bid & 7) * cpx + (bid >> 3);
    const int by  = sw / nbx;
    const int bx  = sw - by * nbx;
    const size_t m0 = (size_t)by * 128;
    const int n0 = bx * 128;

    const unsigned short* Bl = Bh + 256;

    f32x4 acc[4][4];
#pragma unroll
    for (int i = 0; i < 4; ++i)
#pragma unroll
        for (int j = 0; j < 4; ++j) {
            f32x4 z = {0.f, 0.f, 0.f, 0.f};
            acc[i][j] = z;
        }

#define GLL(gp, smb, ldsByteOff)                                                     \
    __builtin_amdgcn_global_load_lds(                                                \
        (const __attribute__((address_space(1))) void*)(gp),                         \
        (__attribute__((address_space(3))) void*)((smb) + (ldsByteOff)), 16, 0, 0)

    // Stage one K-tile. 512 cells per operand tile (128 rows x 4 slots of
    // 16B); pass p covers cells p*256+tid -> per-lane dest stride 16
    // (contiguous in lane order — the global_load_lds requirement).
    // Source k-slot pre-swizzled with the read-side involution.
#define STAGE(bufp, k0)                                                              \
    {                                                                                \
        char* smb_ = (char*)(bufp);                                                  \
        _Pragma("unroll")                                                            \
        for (int p_ = 0; p_ < 2; ++p_) {                                             \
            const int c_ = p_ * 256 + tid;                                           \
            const int row_ = c_ >> 2;                                                \
            const int sl_  = (c_ & 3) ^ ((row_ >> 1) & 3);                           \
            const size_t ga_ = (size_t)(m0 + row_) * lda + (k0) + sl_ * 8;           \
            GLL(Ah + ga_, smb_, (unsigned)c_ * 16u);                                 \
        }                                                                            \
        _Pragma("unroll")                                                            \
        for (int p_ = 0; p_ < 2; ++p_) {                                             \
            const int c_ = p_ * 256 + tid;                                           \
            const int row_ = c_ >> 2;                                                \
            const int sl_  = (c_ & 3) ^ ((row_ >> 1) & 3);                           \
            const size_t gb_ = (size_t)(n0 + row_) * ldb + (k0) + sl_ * 8;           \
            GLL(Bh + gb_, smb_, 8192u  + (unsigned)c_ * 16u);                        \
            GLL(Bl + gb_, smb_, 16384u + (unsigned)c_ * 16u);                        \
        }                                                                            \
    }

    STAGE(sm[0], 0);

#pragma unroll
    for (int t = 0; t < 8; ++t) {
        const int cur = t & 1;
        if (t < 7) {
            STAGE(sm[cur ^ 1], (t + 1) * 32);
            asm volatile("s_waitcnt vmcnt(6)" ::: "memory");
        } else {
            asm volatile("s_waitcnt vmcnt(0)" ::: "memory");
        }
        __builtin_amdgcn_s_barrier();
        __builtin_amdgcn_sched_barrier(0);

        char* smb = (char*)sm[cur];
        const int sR = lane >> 4;
        f16x8 fa[4], fbh[4], fbl[4];
#pragma unroll
        for (int i = 0; i < 4; ++i) {
            const int ra = wm * 64 + i * 16 + (lane & 15);
            const int oa = ra * 64 + ((sR ^ ((ra >> 1) & 3)) * 16);
            fa[i] = *(const f16x8*)(smb + oa);
            const int rb = wn * 64 + i * 16 + (lane & 15);
            const int ob = rb * 64 + ((sR ^ ((rb >> 1) & 3)) * 16);
            fbh[i] = *(const f16x8*)(smb + 8192 + ob);
            fbl[i] = *(const f16x8*)(smb + 16384 + ob);
        }
        // Swapped operands: D-row <-> B row (n), D-col <-> A row (m).
        __builtin_amdgcn_s_setprio(1);
#pragma unroll
        for (int i = 0; i < 4; ++i)
#pragma unroll
            for (int j = 0; j < 4; ++j) {
                acc[i][j] = __builtin_amdgcn_mfma_f32_16x16x32_f16(fbh[j], fa[i], acc[i][j], 0, 0, 0);
                acc[i][j] = __builtin_amdgcn_mfma_f32_16x16x32_f16(fbl[j], fa[i], acc[i][j], 0, 0, 0);
            }
        __builtin_amdgcn_s_setprio(0);
        __builtin_amdgcn_sched_barrier(0);
        if (t < 7)
            __builtin_amdgcn_s_barrier();
    }
#undef STAGE
#undef GLL

    // ---- epilogue: lane holds C[m][n..n+3] -> float4 stores ----
#pragma unroll
    for (int j = 0; j < 4; ++j) {
        const int nb = n0 + wn * 64 + j * 16 + ((lane >> 4) << 2);
        float4 bv = {0.f, 0.f, 0.f, 0.f};
        if (bias) bv = *(const float4*)(bias + nb);
#pragma unroll
        for (int i = 0; i < 4; ++i) {
            const size_t m = m0 + wm * 64 + i * 16 + (lane & 15);
            float4 o;
            o.x = acc[i][j][0] + bv.x;
            o.y = acc[i][j][1] + bv.y;
            o.z = acc[i][j][2] + bv.z;
            o.w = acc[i][j][3] + bv.w;
            *(float4*)(Cc + m * ldc + nb) = o;
        }
    }
}

// ---------------------------------------------------------------------------
// kvpart + column exp-sums. XCD batch-affine. Unchanged from R12.
// ---------------------------------------------------------------------------
__global__ __launch_bounds__(256) void kv_partial(
    const float* __restrict__ qkv, float* __restrict__ kvpart,
    float* __restrict__ sp)
{
    const int bid0  = blockIdx.x;   // 1024 blocks
    const int bid   = (bid0 & 7) * 128 + (bid0 >> 3);   // XCD b -> batch b
    const int chunk = bid & 15;
    const int bh    = bid >> 4;
    const int b     = bh >> 3, hh = bh & 7;
    const int tid   = threadIdx.x;

    __shared__ float smem[4096];
    float* ks = smem;
    float* vs = smem + 2048;

    const int c  = tid & 31;
    const int rs = tid >> 5;
    const float* kbase = qkv + (size_t)b * N_ * C3_ + C_ + hh * 32 + c;
    const float* vbase = qkv + (size_t)b * N_ * C3_ + 2 * C_ + hh * 32 + c;

    const int s   = tid >> 6;
    const int lan = tid & 63;
    const int ckg = (lan >> 3) & 7;
    const int cvg = lan & 7;

    float acc[4][4] = {};
    float sStage = 0.f;

    for (int t = 0; t < 4; ++t) {
        const int nb = chunk * 256 + t * 64;
#pragma unroll
        for (int u = 0; u < 8; ++u) {
            const int i = u * 8 + rs;
            const size_t off = (size_t)(nb + i) * C3_;
            const float ev = __expf(kbase[off]);
            ks[i * 32 + c] = ev;
            sStage += ev;
            vs[i * 32 + c] = vbase[off];
        }
        __syncthreads();
#pragma unroll
        for (int i = 0; i < 16; ++i) {
            const int row = s * 16 + i;
            const float4 k4 = *(const float4*)&ks[row * 32 + ckg * 4];
            const float4 v4 = *(const float4*)&vs[row * 32 + cvg * 4];
            const float ka[4] = {k4.x, k4.y, k4.z, k4.w};
            const float va[4] = {v4.x, v4.y, v4.z, v4.w};
#pragma unroll
            for (int a = 0; a < 4; ++a)
#pragma unroll
                for (int bb = 0; bb < 4; ++bb)
                    acc[a][bb] = fmaf(ka[a], va[bb], acc[a][bb]);
        }
        __syncthreads();
    }

#pragma unroll
    for (int a = 0; a < 4; ++a) {
        float4 w;
        w.x = acc[a][0]; w.y = acc[a][1]; w.z = acc[a][2]; w.w = acc[a][3];
        *(float4*)&smem[s * 1024 + (ckg * 4 + a) * 32 + cvg * 4] = w;
    }
    __syncthreads();
    {
        const int i0 = tid * 4;
        float4 r0 = *(const float4*)&smem[i0];
        float4 r1 = *(const float4*)&smem[1024 + i0];
        float4 r2 = *(const float4*)&smem[2048 + i0];
        float4 r3 = *(const float4*)&smem[3072 + i0];
        float4 o;
        o.x = r0.x + r1.x + r2.x + r3.x;
        o.y = r0.y + r1.y + r2.y + r3.y;
        o.z = r0.z + r1.z + r2.z + r3.z;
        o.w = r0.w + r1.w + r2.w + r3.w;
        *(float4*)&kvpart[(size_t)bid * 1024 + i0] = o;
    }
    __syncthreads();
    smem[rs * 32 + c] = sStage;
    __syncthreads();
    if (tid < 32) {
        float S = 0.f;
#pragma unroll
        for (int i = 0; i < 8; ++i) S += smem[i * 32 + tid];
        sp[(size_t)bid * 32 + tid] = S;
    }
}

__global__ __launch_bounds__(1024) void kv_reduce(
    const float* __restrict__ kvpart, const float* __restrict__ sp,
    float* __restrict__ kv)
{
    const int bid0 = blockIdx.x;    // 64 blocks
    const int bh   = (bid0 & 7) * 8 + (bid0 >> 3);
    const int j  = threadIdx.x;
    const int ck = j >> 5;
    float s = 0.f, ssum = 0.f;
#pragma unroll
    for (int t = 0; t < 16; ++t) s += kvpart[(size_t)(bh * 16 + t) * 1024 + j];
#pragma unroll
    for (int t = 0; t < 16; ++t) ssum += sp[(size_t)(bh * 16 + t) * 32 + ck];
    kv[(size_t)bh * 1024 + j] = s / ssum;
}

// ---------------------------------------------------------------------------
// FUSED conv + combine. XCD batch-affine. Output fp16 (single) into the
// dead k columns of qkv — gemm2's A operand (W-side carries the hi/lo pair).
// ---------------------------------------------------------------------------
__global__ __launch_bounds__(256) void attn_fused(
    float* __restrict__ qkv, const float* __restrict__ kv,
    const float* __restrict__ kern, const float* __restrict__ kbias)
{
    const int bid0 = blockIdx.x;     // 2048 blocks
    const int bid  = (bid0 & 7) * 256 + (bid0 >> 3);
    const int rb = bid & 255, b = bid >> 8;
    const int y  = rb >> 2;
    const int x0 = (rb & 3) * 16;
    const size_t row0 = (size_t)b * N_ + rb * 16;
    const int tid = threadIdx.x;

    __shared__ float kvs[8192];
    __shared__ float qs[16 * 288];
    __shared__ float cvs[16 * 256];

    {
        const float* kvsrc = kv + (size_t)b * 8192;
#pragma unroll
        for (int u = 0; u < 8; ++u) {
            const int idx = u * 1024 + tid * 4;
            *(float4*)&kvs[idx] = *(const float4*)&kvsrc[idx];
        }
    }
    const int sdst = (tid >> 5) * 36 + (tid & 31);
#pragma unroll
    for (int r = 0; r < 16; ++r)
        qs[r * 288 + sdst] = qkv[(row0 + r) * C3_ + tid];

    {
        const int c = tid;
        float kw[9];
#pragma unroll
        for (int q = 0; q < 9; ++q) kw[q] = kern[c * 9 + q];
        const float bb = kbias[c];

        const float* vb = qkv + (size_t)b * N_ * C3_ + 2 * C_ + c;
        float win[3][18];
#pragma unroll
        for (int dy = 0; dy < 3; ++dy) {
            const int yy = y + dy - 1;
            const bool oky = (yy >= 0) && (yy < 64);
#pragma unroll
            for (int dx = 0; dx < 18; ++dx) {
                const int xx = x0 + dx - 1;
                const bool ok = oky && (xx >= 0) && (xx < 64);
                win[dy][dx] = ok ? vb[(size_t)(yy * 64 + xx) * C3_] : 0.f;
            }
        }
#pragma unroll
        for (int xo = 0; xo < 16; ++xo) {
            float o = bb;
#pragma unroll
            for (int dy = 0; dy < 3; ++dy) {
                o = fmaf(kw[dy * 3 + 0], win[dy][xo + 0], o);
                o = fmaf(kw[dy * 3 + 1], win[dy][xo + 1], o);
                o = fmaf(kw[dy * 3 + 2], win[dy][xo + 2], o);
            }
            cvs[xo * 256 + c] = o;
        }
    }
    __syncthreads();

    const int rg  = tid >> 6;
    const int cg  = tid & 63;
    const int hh  = cg >> 3;
    const int cv0 = (cg & 7) * 4;
    const float scale = 0.17677669529663687f;

    float acc[4][4] = {};
    for (int ck = 0; ck < 32; ++ck) {
        const float4 kv4 = *(const float4*)&kvs[hh * 1024 + ck * 32 + cv0];
        const float kva[4] = {kv4.x, kv4.y, kv4.z, kv4.w};
#pragma unroll
        for (int ri = 0; ri < 4; ++ri) {
            const float qv = qs[(rg * 4 + ri) * 288 + hh * 36 + ck];
#pragma unroll
            for (int bb = 0; bb < 4; ++bb)
                acc[ri][bb] = fmaf(qv, kva[bb], acc[ri][bb]);
        }
    }

#pragma unroll
    for (int ri = 0; ri < 4; ++ri) {
        const int r = rg * 4 + ri;
        const float4 q4 = *(const float4*)&qs[r * 288 + hh * 36 + cv0];
        const float4 cw = *(const float4*)&cvs[r * 256 + cg * 4];
        const float qa[4]  = {q4.x, q4.y, q4.z, q4.w};
        const float cwa[4] = {cw.x, cw.y, cw.z, cw.w};
        ushort4 hv;
        hv.x = f2h(fmaf(qa[0], cwa[0], scale * acc[ri][0]));
        hv.y = f2h(fmaf(qa[1], cwa[1], scale * acc[ri][1]));
        hv.z = f2h(fmaf(qa[2], cwa[2], scale * acc[ri][2]));
        hv.w = f2h(fmaf(qa[3], cwa[3], scale * acc[ri][3]));
        unsigned short* kreg = (unsigned short*)(qkv + (row0 + r) * C3_ + C_);
        *(ushort4*)&kreg[cg * 4] = hv;
    }
}

// ---------------------------------------------------------------------------
extern "C" void kernel_launch(void* const* d_in, const int* in_sizes, int n_in,
                              void* d_out, int out_size, void* d_ws, size_t ws_size,
                              hipStream_t stream)
{
    const float* x     = (const float*)d_in[0];
    const float* Wqkv  = (const float*)d_in[1];
    const float* Wproj = (const float*)d_in[2];
    const float* bproj = (const float*)d_in[3];
    const float* kern  = (const float*)d_in[4];
    const float* kbias = (const float*)d_in[5];

    float* ws     = (float*)d_ws;
    float* qkv    = ws + OFF_QKV;
    float* kv     = ws + OFF_KV;
    float* spart  = ws + OFF_SPART;
    float* kvpart = ws + OFF_CONVV;                            // reuses xh region (dead after gemm1)
    float* out    = (float*)d_out;

    unsigned short* xh  = (unsigned short*)(ws + OFF_CONVV);   // fp16 x, live only for gemm1
    unsigned short* whl = (unsigned short*)(ws + OFF_WHL);     // fp16 hi/lo weights

    // 0) x -> fp16, weights -> fp16 hi/lo (one launch)
    convert_all<<<8448, 256, 0, stream>>>(x, Wqkv, Wproj, xh, whl);
    // 1) qkv = x @ Wqkv^T via fp16 2-MFMA emulation   [32768 x 768]
    gemm_f16_mfma<<<dim3(6, 256), 256, 0, stream>>>(xh, 256, whl, 512, qkv, C3_, nullptr);
    // 2) kv = softmax(k)^T @ v per (b,h): split-N partials + reduce
    kv_partial<<<1024, 256, 0, stream>>>(qkv, kvpart, spart);
    kv_reduce<<<64, 1024, 0, stream>>>(kvpart, spart, kv);
    // 3) FUSED conv + combine (XCD batch-affine): tmp -> fp16 into k-cols
    attn_fused<<<2048, 256, 0, stream>>>(qkv, kv, kern, kbias);
    // 4) out = tmp @ Wproj^T + bproj via fp16 2-MFMA emulation   [32768 x 256]
    gemm_f16_mfma<<<dim3(2, 256), 256, 0, stream>>>((unsigned short*)qkv + 512, 1536,
                                                    whl + (size_t)768 * 512, 512, out, C_, bproj);
}

// Round 16
// 93.977 us; speedup vs baseline: 1.3110x; 1.1196x over previous
//
#include <hip/hip_runtime.h>
#include <cstdint>
#include <cstddef>

// Problem constants
#define B_   8
#define N_   4096
#define C_   256
#define C3_  768
#define NH_  8
#define CH_  32

// Workspace layout (in floats).
static const size_t OFF_QKV    = 0;          // [B*N, 768] fp32 (q|k|v). k cols reused as fp16 attn output for gemm2
static const size_t OFF_CONVV  = 25165824;   // Xh fp16[32768][256] for gemm1, then kvpart
static const size_t OFF_KV     = 33554432;   // [B*h, 32, 32]
static const size_t OFF_WH     = 33619968;   // Wh fp16[1024][256]: rows 0..767 Wqkv, 768..1023 Wproj
static const size_t OFF_SPART  = 34144256;   // [B*h, 16, 32] column exp-sums

typedef __attribute__((ext_vector_type(4))) float f32x4;
typedef __attribute__((ext_vector_type(8))) _Float16 f16x8;   // 8 fp16 = 4 VGPRs

__device__ __forceinline__ unsigned short f2h(float f) {
    return __builtin_bit_cast(unsigned short, (_Float16)f);   // RTNE
}

// ---------------------------------------------------------------------------
// Single launch converting x, Wqkv, Wproj -> fp16. x-branch XCD batch-affine.
// ---------------------------------------------------------------------------
__global__ __launch_bounds__(256) void convert_all(
    const float* __restrict__ x, const float* __restrict__ wqkv,
    const float* __restrict__ wproj, unsigned short* __restrict__ xh,
    unsigned short* __restrict__ wh)
{
    int bid = blockIdx.x;
    const float* in;
    unsigned short* out;
    if (bid < 8192) {
        in = x; out = xh;
        bid = (bid & 7) * 1024 + (bid >> 3);                  // XCD b -> batch b
    } else if (bid < 8384) { in = wqkv;  out = wh;                      bid -= 8192; }
    else                   { in = wproj; out = wh + (size_t)768 * 256;  bid -= 8384; }

    const int idx = bid * 256 + threadIdx.x;
    const int r = idx >> 6, q = idx & 63;
    const float4 v = *(const float4*)(in + (size_t)r * 256 + q * 4);
    ushort4 hv;
    hv.x = f2h(v.x); hv.y = f2h(v.y); hv.z = f2h(v.z); hv.w = f2h(v.w);
    *(ushort4*)(out + (size_t)r * 256 + q * 4) = hv;
}

// ---------------------------------------------------------------------------
// Pure fp16 MFMA GEMM: C = A_fp16 @ B_fp16^T (+ bias), fp32 accumulate.
// 128x128 tile, BK=32, 4 waves (2x2 of 64x64) — the verified counted-vmcnt
// double-buffer skeleton. Per buffer: A 8 KB | B 8 KB = 16 KB; dbuf 32 KB ->
// 4+ blocks/CU. 4 GLL/thread/tile (per-lane LDS dest stride 16, contiguous
// in lane order — the global_load_lds requirement), vmcnt(4): next tile's
// loads stay in flight across the barrier. 16 MFMA/step.
// ---------------------------------------------------------------------------
__global__ __launch_bounds__(256, 4) void gemm_f16_mfma(
    const unsigned short* __restrict__ Ah, int lda,
    const unsigned short* __restrict__ Bh, int ldb,
    float* __restrict__ Cc, int ldc,
    const float* __restrict__ bias)
{
    __shared__ __align__(128) unsigned short sm[2][8192];   // 32 KB
    const int tid  = threadIdx.x;
    const int lane = tid & 63;
    const int wv   = tid >> 6;
    const int wm   = wv >> 1, wn = wv & 1;

    // XCD-chunked swizzle (nwg % 8 == 0 for both launches)
    const int nbx = gridDim.x;
    const int nwg = nbx * gridDim.y;
    const int bid = blockIdx.y * nbx + blockIdx.x;
    const int cpx = nwg >> 3;
    const int sw  = (bid & 7) * cpx + (bid >> 3);
    const int by  = sw / nbx;
    const int bx  = sw - by * nbx;
    const size_t m0 = (size_t)by * 128;
    const int n0 = bx * 128;

    f32x4 acc[4][4];
#pragma unroll
    for (int i = 0; i < 4; ++i)
#pragma unroll
        for (int j = 0; j < 4; ++j) {
            f32x4 z = {0.f, 0.f, 0.f, 0.f};
            acc[i][j] = z;
        }

#define GLL(gp, smb, ldsByteOff)                                                     \
    __builtin_amdgcn_global_load_lds(                                                \
        (const __attribute__((address_space(1))) void*)(gp),                         \
        (__attribute__((address_space(3))) void*)((smb) + (ldsByteOff)), 16, 0, 0)

    // Stage one K-tile. 512 cells per operand (128 rows x 4 slots of 16B);
    // pass p covers cells p*256+tid. Source k-slot pre-swizzled with the
    // read-side involution slot ^ ((row>>1)&3); LDS linear.
#define STAGE(bufp, k0)                                                              \
    {                                                                                \
        char* smb_ = (char*)(bufp);                                                  \
        _Pragma("unroll")                                                            \
        for (int p_ = 0; p_ < 2; ++p_) {                                             \
            const int c_ = p_ * 256 + tid;                                           \
            const int row_ = c_ >> 2;                                                \
            const int sl_  = (c_ & 3) ^ ((row_ >> 1) & 3);                           \
            const size_t ga_ = (size_t)(m0 + row_) * lda + (k0) + sl_ * 8;           \
            GLL(Ah + ga_, smb_, (unsigned)c_ * 16u);                                 \
        }                                                                            \
        _Pragma("unroll")                                                            \
        for (int p_ = 0; p_ < 2; ++p_) {                                             \
            const int c_ = p_ * 256 + tid;                                           \
            const int row_ = c_ >> 2;                                                \
            const int sl_  = (c_ & 3) ^ ((row_ >> 1) & 3);                           \
            const size_t gb_ = (size_t)(n0 + row_) * ldb + (k0) + sl_ * 8;           \
            GLL(Bh + gb_, smb_, 8192u + (unsigned)c_ * 16u);                         \
        }                                                                            \
    }

    STAGE(sm[0], 0);

#pragma unroll
    for (int t = 0; t < 8; ++t) {
        const int cur = t & 1;
        if (t < 7) {
            STAGE(sm[cur ^ 1], (t + 1) * 32);
            asm volatile("s_waitcnt vmcnt(4)" ::: "memory");
        } else {
            asm volatile("s_waitcnt vmcnt(0)" ::: "memory");
        }
        __builtin_amdgcn_s_barrier();
        __builtin_amdgcn_sched_barrier(0);

        char* smb = (char*)sm[cur];
        const int sR = lane >> 4;
        f16x8 fa[4], fb[4];
#pragma unroll
        for (int i = 0; i < 4; ++i) {
            const int ra = wm * 64 + i * 16 + (lane & 15);
            const int oa = ra * 64 + ((sR ^ ((ra >> 1) & 3)) * 16);
            fa[i] = *(const f16x8*)(smb + oa);
            const int rb = wn * 64 + i * 16 + (lane & 15);
            const int ob = rb * 64 + ((sR ^ ((rb >> 1) & 3)) * 16);
            fb[i] = *(const f16x8*)(smb + 8192 + ob);
        }
        // Swapped operands: D-row <-> B row (n), D-col <-> A row (m).
        __builtin_amdgcn_s_setprio(1);
#pragma unroll
        for (int i = 0; i < 4; ++i)
#pragma unroll
            for (int j = 0; j < 4; ++j)
                acc[i][j] = __builtin_amdgcn_mfma_f32_16x16x32_f16(fb[j], fa[i], acc[i][j], 0, 0, 0);
        __builtin_amdgcn_s_setprio(0);
        __builtin_amdgcn_sched_barrier(0);
        if (t < 7)
            __builtin_amdgcn_s_barrier();
    }
#undef STAGE
#undef GLL

    // ---- epilogue: lane holds C[m][n..n+3] -> float4 stores ----
#pragma unroll
    for (int j = 0; j < 4; ++j) {
        const int nb = n0 + wn * 64 + j * 16 + ((lane >> 4) << 2);
        float4 bv = {0.f, 0.f, 0.f, 0.f};
        if (bias) bv = *(const float4*)(bias + nb);
#pragma unroll
        for (int i = 0; i < 4; ++i) {
            const size_t m = m0 + wm * 64 + i * 16 + (lane & 15);
            float4 o;
            o.x = acc[i][j][0] + bv.x;
            o.y = acc[i][j][1] + bv.y;
            o.z = acc[i][j][2] + bv.z;
            o.w = acc[i][j][3] + bv.w;
            *(float4*)(Cc + m * ldc + nb) = o;
        }
    }
}

// ---------------------------------------------------------------------------
// kvpart + column exp-sums. XCD batch-affine. Unchanged from R12.
// ---------------------------------------------------------------------------
__global__ __launch_bounds__(256) void kv_partial(
    const float* __restrict__ qkv, float* __restrict__ kvpart,
    float* __restrict__ sp)
{
    const int bid0  = blockIdx.x;   // 1024 blocks
    const int bid   = (bid0 & 7) * 128 + (bid0 >> 3);   // XCD b -> batch b
    const int chunk = bid & 15;
    const int bh    = bid >> 4;
    const int b     = bh >> 3, hh = bh & 7;
    const int tid   = threadIdx.x;

    __shared__ float smem[4096];
    float* ks = smem;
    float* vs = smem + 2048;

    const int c  = tid & 31;
    const int rs = tid >> 5;
    const float* kbase = qkv + (size_t)b * N_ * C3_ + C_ + hh * 32 + c;
    const float* vbase = qkv + (size_t)b * N_ * C3_ + 2 * C_ + hh * 32 + c;

    const int s   = tid >> 6;
    const int lan = tid & 63;
    const int ckg = (lan >> 3) & 7;
    const int cvg = lan & 7;

    float acc[4][4] = {};
    float sStage = 0.f;

    for (int t = 0; t < 4; ++t) {
        const int nb = chunk * 256 + t * 64;
#pragma unroll
        for (int u = 0; u < 8; ++u) {
            const int i = u * 8 + rs;
            const size_t off = (size_t)(nb + i) * C3_;
            const float ev = __expf(kbase[off]);
            ks[i * 32 + c] = ev;
            sStage += ev;
            vs[i * 32 + c] = vbase[off];
        }
        __syncthreads();
#pragma unroll
        for (int i = 0; i < 16; ++i) {
            const int row = s * 16 + i;
            const float4 k4 = *(const float4*)&ks[row * 32 + ckg * 4];
            const float4 v4 = *(const float4*)&vs[row * 32 + cvg * 4];
            const float ka[4] = {k4.x, k4.y, k4.z, k4.w};
            const float va[4] = {v4.x, v4.y, v4.z, v4.w};
#pragma unroll
            for (int a = 0; a < 4; ++a)
#pragma unroll
                for (int bb = 0; bb < 4; ++bb)
                    acc[a][bb] = fmaf(ka[a], va[bb], acc[a][bb]);
        }
        __syncthreads();
    }

#pragma unroll
    for (int a = 0; a < 4; ++a) {
        float4 w;
        w.x = acc[a][0]; w.y = acc[a][1]; w.z = acc[a][2]; w.w = acc[a][3];
        *(float4*)&smem[s * 1024 + (ckg * 4 + a) * 32 + cvg * 4] = w;
    }
    __syncthreads();
    {
        const int i0 = tid * 4;
        float4 r0 = *(const float4*)&smem[i0];
        float4 r1 = *(const float4*)&smem[1024 + i0];
        float4 r2 = *(const float4*)&smem[2048 + i0];
        float4 r3 = *(const float4*)&smem[3072 + i0];
        float4 o;
        o.x = r0.x + r1.x + r2.x + r3.x;
        o.y = r0.y + r1.y + r2.y + r3.y;
        o.z = r0.z + r1.z + r2.z + r3.z;
        o.w = r0.w + r1.w + r2.w + r3.w;
        *(float4*)&kvpart[(size_t)bid * 1024 + i0] = o;
    }
    __syncthreads();
    smem[rs * 32 + c] = sStage;
    __syncthreads();
    if (tid < 32) {
        float S = 0.f;
#pragma unroll
        for (int i = 0; i < 8; ++i) S += smem[i * 32 + tid];
        sp[(size_t)bid * 32 + tid] = S;
    }
}

__global__ __launch_bounds__(1024) void kv_reduce(
    const float* __restrict__ kvpart, const float* __restrict__ sp,
    float* __restrict__ kv)
{
    const int bid0 = blockIdx.x;    // 64 blocks
    const int bh   = (bid0 & 7) * 8 + (bid0 >> 3);
    const int j  = threadIdx.x;
    const int ck = j >> 5;
    float s = 0.f, ssum = 0.f;
#pragma unroll
    for (int t = 0; t < 16; ++t) s += kvpart[(size_t)(bh * 16 + t) * 1024 + j];
#pragma unroll
    for (int t = 0; t < 16; ++t) ssum += sp[(size_t)(bh * 16 + t) * 32 + ck];
    kv[(size_t)bh * 1024 + j] = s / ssum;
}

// ---------------------------------------------------------------------------
// FUSED conv + combine. XCD batch-affine. Output fp16 into the dead k
// columns of qkv — gemm2's A operand.
// ---------------------------------------------------------------------------
__global__ __launch_bounds__(256) void attn_fused(
    float* __restrict__ qkv, const float* __restrict__ kv,
    const float* __restrict__ kern, const float* __restrict__ kbias)
{
    const int bid0 = blockIdx.x;     // 2048 blocks
    const int bid  = (bid0 & 7) * 256 + (bid0 >> 3);
    const int rb = bid & 255, b = bid >> 8;
    const int y  = rb >> 2;
    const int x0 = (rb & 3) * 16;
    const size_t row0 = (size_t)b * N_ + rb * 16;
    const int tid = threadIdx.x;

    __shared__ float kvs[8192];
    __shared__ float qs[16 * 288];
    __shared__ float cvs[16 * 256];

    {
        const float* kvsrc = kv + (size_t)b * 8192;
#pragma unroll
        for (int u = 0; u < 8; ++u) {
            const int idx = u * 1024 + tid * 4;
            *(float4*)&kvs[idx] = *(const float4*)&kvsrc[idx];
        }
    }
    const int sdst = (tid >> 5) * 36 + (tid & 31);
#pragma unroll
    for (int r = 0; r < 16; ++r)
        qs[r * 288 + sdst] = qkv[(row0 + r) * C3_ + tid];

    {
        const int c = tid;
        float kw[9];
#pragma unroll
        for (int q = 0; q < 9; ++q) kw[q] = kern[c * 9 + q];
        const float bb = kbias[c];

        const float* vb = qkv + (size_t)b * N_ * C3_ + 2 * C_ + c;
        float win[3][18];
#pragma unroll
        for (int dy = 0; dy < 3; ++dy) {
            const int yy = y + dy - 1;
            const bool oky = (yy >= 0) && (yy < 64);
#pragma unroll
            for (int dx = 0; dx < 18; ++dx) {
                const int xx = x0 + dx - 1;
                const bool ok = oky && (xx >= 0) && (xx < 64);
                win[dy][dx] = ok ? vb[(size_t)(yy * 64 + xx) * C3_] : 0.f;
            }
        }
#pragma unroll
        for (int xo = 0; xo < 16; ++xo) {
            float o = bb;
#pragma unroll
            for (int dy = 0; dy < 3; ++dy) {
                o = fmaf(kw[dy * 3 + 0], win[dy][xo + 0], o);
                o = fmaf(kw[dy * 3 + 1], win[dy][xo + 1], o);
                o = fmaf(kw[dy * 3 + 2], win[dy][xo + 2], o);
            }
            cvs[xo * 256 + c] = o;
        }
    }
    __syncthreads();

    const int rg  = tid >> 6;
    const int cg  = tid & 63;
    const int hh  = cg >> 3;
    const int cv0 = (cg & 7) * 4;
    const float scale = 0.17677669529663687f;

    float acc[4][4] = {};
    for (int ck = 0; ck < 32; ++ck) {
        const float4 kv4 = *(const float4*)&kvs[hh * 1024 + ck * 32 + cv0];
        const float kva[4] = {kv4.x, kv4.y, kv4.z, kv4.w};
#pragma unroll
        for (int ri = 0; ri < 4; ++ri) {
            const float qv = qs[(rg * 4 + ri) * 288 + hh * 36 + ck];
#pragma unroll
            for (int bb = 0; bb < 4; ++bb)
                acc[ri][bb] = fmaf(qv, kva[bb], acc[ri][bb]);
        }
    }

#pragma unroll
    for (int ri = 0; ri < 4; ++ri) {
        const int r = rg * 4 + ri;
        const float4 q4 = *(const float4*)&qs[r * 288 + hh * 36 + cv0];
        const float4 cw = *(const float4*)&cvs[r * 256 + cg * 4];
        const float qa[4]  = {q4.x, q4.y, q4.z, q4.w};
        const float cwa[4] = {cw.x, cw.y, cw.z, cw.w};
        ushort4 hv;
        hv.x = f2h(fmaf(qa[0], cwa[0], scale * acc[ri][0]));
        hv.y = f2h(fmaf(qa[1], cwa[1], scale * acc[ri][1]));
        hv.z = f2h(fmaf(qa[2], cwa[2], scale * acc[ri][2]));
        hv.w = f2h(fmaf(qa[3], cwa[3], scale * acc[ri][3]));
        unsigned short* kreg = (unsigned short*)(qkv + (row0 + r) * C3_ + C_);
        *(ushort4*)&kreg[cg * 4] = hv;
    }
}

// ---------------------------------------------------------------------------
extern "C" void kernel_launch(void* const* d_in, const int* in_sizes, int n_in,
                              void* d_out, int out_size, void* d_ws, size_t ws_size,
                              hipStream_t stream)
{
    const float* x     = (const float*)d_in[0];
    const float* Wqkv  = (const float*)d_in[1];
    const float* Wproj = (const float*)d_in[2];
    const float* bproj = (const float*)d_in[3];
    const float* kern  = (const float*)d_in[4];
    const float* kbias = (const float*)d_in[5];

    float* ws     = (float*)d_ws;
    float* qkv    = ws + OFF_QKV;
    float* kv     = ws + OFF_KV;
    float* spart  = ws + OFF_SPART;
    float* kvpart = ws + OFF_CONVV;                            // reuses xh region (dead after gemm1)
    float* out    = (float*)d_out;

    unsigned short* xh = (unsigned short*)(ws + OFF_CONVV);    // fp16 x, live only for gemm1
    unsigned short* wh = (unsigned short*)(ws + OFF_WH);       // fp16 weights

    // 0) x, Wqkv, Wproj -> fp16 (one launch)
    convert_all<<<8448, 256, 0, stream>>>(x, Wqkv, Wproj, xh, wh);
    // 1) qkv = x @ Wqkv^T via fp16 MFMA   [32768 x 768]
    gemm_f16_mfma<<<dim3(6, 256), 256, 0, stream>>>(xh, 256, wh, 256, qkv, C3_, nullptr);
    // 2) kv = softmax(k)^T @ v per (b,h): split-N partials + reduce
    kv_partial<<<1024, 256, 0, stream>>>(qkv, kvpart, spart);
    kv_reduce<<<64, 1024, 0, stream>>>(kvpart, spart, kv);
    // 3) FUSED conv + combine (XCD batch-affine): tmp -> fp16 into k-cols
    attn_fused<<<2048, 256, 0, stream>>>(qkv, kv, kern, kbias);
    // 4) out = tmp @ Wproj^T + bproj via fp16 MFMA   [32768 x 256]
    gemm_f16_mfma<<<dim3(2, 256), 256, 0, stream>>>((unsigned short*)qkv + 512, 1536,
                                                    wh + (size_t)768 * 256, 256, out, C_, bproj);
}